// Round 7
// baseline (485.838 us; speedup 1.0000x reference)
//
#include <hip/hip_runtime.h>

// ConnectivityLoss R7: R6 + occupancy & dead-op bundle.
// - launch_bounds(256,4): R6's rolling-window peak-live fits the 128-VGPR cap
//   (R5 spilled at ~140 live; R6 allocated 84). 4 blocks/CU, LDS 159.7 KB.
// - contour = maxpool3(B) - B exactly (center in window => mx >= B): inner
//   relu eliminated, bit-identical.
// - Border fixups behind block/wave-uniform branches: interior waves pay 0.

#define IMG 512
#define TW  32            // output tile width  (16 x-tiles)
#define TH  128           // output tile height (4 y-tiles)
#define SKW 34            // skeleton stash cols [11,44]
#define SKH 130           // skeleton stash rows [11,140]
#define XROW 68           // exchange row stride (floats)
#define XBUF (8*XROW)     // 4 waves x {top,bot}
#define NT  256

struct alignas(16) R8 { float v[8]; };

__device__ __forceinline__ float f3min(float a, float b, float c) {
    return fminf(fminf(a, b), c);
}
__device__ __forceinline__ float f3max(float a, float b, float c) {
    return fmaxf(fmaxf(a, b), c);
}
__device__ __forceinline__ float dpp_up1(float x) {   // lane i <- i-1
    int r = __builtin_amdgcn_update_dpp(
        0, __builtin_bit_cast(int, x), 0x111, 0xF, 0xF, true); // row_shr:1
    return __builtin_bit_cast(float, r);
}
__device__ __forceinline__ float dpp_dn1(float x) {   // lane i <- i+1
    int r = __builtin_amdgcn_update_dpp(
        0, __builtin_bit_cast(int, x), 0x101, 0xF, 0xF, true); // row_shl:1
    return __builtin_bit_cast(float, r);
}
__device__ __forceinline__ float bpermf(int addr, float x) {
    return __builtin_bit_cast(float,
        __builtin_amdgcn_ds_bpermute(addr, __builtin_bit_cast(int, x)));
}

// horizontal 3-tap; le/ri from strip s-1/s+1 (lane -8/+8).
// Image-edge tap-drop only inside block-uniform lB/rB branches.
template<bool MN>
__device__ __forceinline__ void hrow(const R8& r, R8& h, bool lB, bool rB,
                                     int s, int aL, int aR) {
    float le = bpermf(aL, r.v[7]);
    float ri = bpermf(aR, r.v[0]);
    if (MN) {
        h.v[0] = f3min(le,     r.v[0], r.v[1]);
        h.v[1] = f3min(r.v[0], r.v[1], r.v[2]);
        h.v[2] = f3min(r.v[1], r.v[2], r.v[3]);
        h.v[3] = f3min(r.v[2], r.v[3], r.v[4]);
        h.v[4] = f3min(r.v[3], r.v[4], r.v[5]);
        h.v[5] = f3min(r.v[4], r.v[5], r.v[6]);
        h.v[6] = f3min(r.v[5], r.v[6], r.v[7]);
        h.v[7] = f3min(r.v[6], r.v[7], ri);
        if (lB) { if (s == 1) h.v[4] = fminf(r.v[4], r.v[5]); }  // gx==0
        if (rB) { if (s == 5) h.v[3] = fminf(r.v[2], r.v[3]); }  // gx==511
    } else {
        h.v[0] = f3max(le,     r.v[0], r.v[1]);
        h.v[1] = f3max(r.v[0], r.v[1], r.v[2]);
        h.v[2] = f3max(r.v[1], r.v[2], r.v[3]);
        h.v[3] = f3max(r.v[2], r.v[3], r.v[4]);
        h.v[4] = f3max(r.v[3], r.v[4], r.v[5]);
        h.v[5] = f3max(r.v[4], r.v[5], r.v[6]);
        h.v[6] = f3max(r.v[5], r.v[6], r.v[7]);
        h.v[7] = f3max(r.v[6], r.v[7], ri);
        if (lB) { if (s == 1) h.v[4] = fmaxf(r.v[4], r.v[5]); }
        if (rB) { if (s == 5) h.v[3] = fmaxf(r.v[2], r.v[3]); }
    }
}

__global__ __launch_bounds__(NT, 4)
void skel_conn_loss(const float* __restrict__ pred,
                    const float* __restrict__ target,
                    float* __restrict__ out)
{
    __shared__ float X[2*XBUF];          // boundary-row exchange dbuf (4.35KB)
    __shared__ float SKP[SKH*SKW];       // pred skeleton
    __shared__ float SKT[SKH*SKW];       // target skeleton
    __shared__ float red[4];

    const int tid  = threadIdx.x;
    const int wv   = tid >> 6;           // wave 0..3 owns rows 40w..40w+39
    const int lane = tid & 63;
    const int s    = lane >> 3;          // 8-col strip
    const int gq   = lane & 7;           // row group (5 rows); +-1 == lane+-1
    const int img  = blockIdx.x >> 6;
    const int rem  = blockIdx.x & 63;
    const int ty0  = (rem >> 4) * TH;
    const int tx0  = (rem & 15) * TW;

    const int c0  = 8*s;
    const int r0  = 40*wv + 5*gq;
    const int gx0 = tx0 - 12 + c0;
    const bool xin = (tx0 > 0) && (tx0 + TW < IMG);

    const bool lB = (tx0 == 0), rB = (tx0 + TW == IMG);        // block-uniform
    const bool vwT = (ty0 == 0)       && (wv == 0);            // wave-uniform
    const bool vwB = (ty0 + TH == IMG) && (wv == 3);
    const int  sw  = 8*s + 4*(s >> 2);               // bank-swizzled exch col
    const int  aL  = ((lane - 8) & 63) * 4;          // bpermute addrs
    const int  aR  = ((lane + 8) & 63) * 4;

    R8 A[5], Bv[5];
    int xb = 0;

    #pragma unroll 1
    for (int t = 0; t < 2; ++t) {
        const float* __restrict__ src =
            (t ? target : pred) + (size_t)img * (IMG * IMG);

        // ---- load strip (addresses clamped; OOB values never consumed) ----
        #pragma unroll
        for (int i = 0; i < 5; ++i) {
            int gy = min(max(ty0 - 12 + r0 + i, 0), IMG - 1);
            const float* rp = src + gy * IMG;
            if (xin) {
                *(float4*)&A[i].v[0] = *(const float4*)(rp + gx0);
                *(float4*)&A[i].v[4] = *(const float4*)(rp + gx0 + 4);
            } else {
                #pragma unroll
                for (int j = 0; j < 8; ++j)
                    A[i].v[j] = rp[min(max(gx0 + j, 0), IMG - 1)];
            }
        }

        #pragma unroll 1
        for (int it = 0; it < 5; ++it) {
            // ================= pass 1: Bv = minpool3(A) =================
            {
                R8 w0, w1, w2, w3, w4, abh, beh;
                hrow<true>(A[4], w4, lB, rB, s, aL, aR);   // feeds exch+DPP
                hrow<true>(A[0], w0, lB, rB, s, aL, aR);
                float* Xb = X + xb * XBUF;
                if (gq == 0) {
                    float* p = Xb + (2*wv) * XROW + sw;
                    *(float4*)p       = *(const float4*)&w0.v[0];
                    *(float4*)(p + 4) = *(const float4*)&w0.v[4];
                }
                if (gq == 7) {
                    float* p = Xb + (2*wv + 1) * XROW + sw;
                    *(float4*)p       = *(const float4*)&w4.v[0];
                    *(float4*)(p + 4) = *(const float4*)&w4.v[4];
                }
                __syncthreads();
                #pragma unroll
                for (int j = 0; j < 8; ++j) {
                    abh.v[j] = dpp_up1(w4.v[j]);   // group above's bottom
                    beh.v[j] = dpp_dn1(w0.v[j]);   // group below's top
                }
                if (gq == 0) {
                    if (wv) {
                        const float* p = Xb + (2*wv - 1) * XROW + sw;
                        *(float4*)&abh.v[0] = *(const float4*)p;
                        *(float4*)&abh.v[4] = *(const float4*)(p + 4);
                    } else abh = w0;               // tile-edge garbage margin
                }
                if (gq == 7) {
                    if (wv < 3) {
                        const float* p = Xb + (2*wv + 2) * XROW + sw;
                        *(float4*)&beh.v[0] = *(const float4*)p;
                        *(float4*)&beh.v[4] = *(const float4*)(p + 4);
                    } else beh = w4;
                }
                hrow<true>(A[1], w1, lB, rB, s, aL, aR);
                #pragma unroll
                for (int j = 0; j < 8; ++j)
                    Bv[0].v[j] = f3min(abh.v[j], w0.v[j], w1.v[j]);
                hrow<true>(A[2], w2, lB, rB, s, aL, aR);
                #pragma unroll
                for (int j = 0; j < 8; ++j)
                    Bv[1].v[j] = f3min(w0.v[j], w1.v[j], w2.v[j]);
                hrow<true>(A[3], w3, lB, rB, s, aL, aR);
                #pragma unroll
                for (int j = 0; j < 8; ++j) {
                    Bv[2].v[j] = f3min(w1.v[j], w2.v[j], w3.v[j]);
                    Bv[3].v[j] = f3min(w2.v[j], w3.v[j], w4.v[j]);
                    Bv[4].v[j] = f3min(w3.v[j], w4.v[j], beh.v[j]);
                }
                if (vwT) {               // wave-uniform: row 12 == gy 0
                    #pragma unroll
                    for (int j = 0; j < 8; ++j) {
                        float alt = fminf(w2.v[j], w3.v[j]);
                        Bv[2].v[j] = (gq == 2) ? alt : Bv[2].v[j];
                    }
                }
                if (vwB) {               // wave-uniform: row 139 == gy 511
                    #pragma unroll
                    for (int j = 0; j < 8; ++j) {
                        float alt = fminf(w3.v[j], w4.v[j]);
                        Bv[4].v[j] = (gq == 3) ? alt : Bv[4].v[j];
                    }
                }
                xb ^= 1;
            }
            // == pass 2: A = relu(A - (maxpool3(Bv) - Bv)), mx>=Bv exact ==
            {
                R8 u0, u1, u2, u3, u4, abh, beh;
                hrow<false>(Bv[4], u4, lB, rB, s, aL, aR);
                hrow<false>(Bv[0], u0, lB, rB, s, aL, aR);
                float* Xb = X + xb * XBUF;
                if (gq == 0) {
                    float* p = Xb + (2*wv) * XROW + sw;
                    *(float4*)p       = *(const float4*)&u0.v[0];
                    *(float4*)(p + 4) = *(const float4*)&u0.v[4];
                }
                if (gq == 7) {
                    float* p = Xb + (2*wv + 1) * XROW + sw;
                    *(float4*)p       = *(const float4*)&u4.v[0];
                    *(float4*)(p + 4) = *(const float4*)&u4.v[4];
                }
                __syncthreads();
                #pragma unroll
                for (int j = 0; j < 8; ++j) {
                    abh.v[j] = dpp_up1(u4.v[j]);
                    beh.v[j] = dpp_dn1(u0.v[j]);
                }
                if (gq == 0) {
                    if (wv) {
                        const float* p = Xb + (2*wv - 1) * XROW + sw;
                        *(float4*)&abh.v[0] = *(const float4*)p;
                        *(float4*)&abh.v[4] = *(const float4*)(p + 4);
                    } else abh = u0;
                }
                if (gq == 7) {
                    if (wv < 3) {
                        const float* p = Xb + (2*wv + 2) * XROW + sw;
                        *(float4*)&beh.v[0] = *(const float4*)p;
                        *(float4*)&beh.v[4] = *(const float4*)(p + 4);
                    } else beh = u4;
                }
                // ct = mx - Bv (>=0 exactly); A = max(A - ct, 0)
                #define UPD(i, MXE)                                            \
                    _Pragma("unroll")                                          \
                    for (int j = 0; j < 8; ++j) {                              \
                        float ct = (MXE) - Bv[i].v[j];                         \
                        A[i].v[j] = fmaxf(A[i].v[j] - ct, 0.0f);               \
                    }
                hrow<false>(Bv[1], u1, lB, rB, s, aL, aR);
                UPD(0, f3max(abh.v[j], u0.v[j], u1.v[j]))
                hrow<false>(Bv[2], u2, lB, rB, s, aL, aR);
                UPD(1, f3max(u0.v[j], u1.v[j], u2.v[j]))
                hrow<false>(Bv[3], u3, lB, rB, s, aL, aR);
                // row 2: vfT patch behind wave-uniform branch
                {
                    R8 mx2;
                    #pragma unroll
                    for (int j = 0; j < 8; ++j)
                        mx2.v[j] = f3max(u1.v[j], u2.v[j], u3.v[j]);
                    if (vwT) {
                        #pragma unroll
                        for (int j = 0; j < 8; ++j) {
                            float alt = fmaxf(u2.v[j], u3.v[j]);
                            mx2.v[j] = (gq == 2) ? alt : mx2.v[j];
                        }
                    }
                    UPD(2, mx2.v[j])
                }
                UPD(3, f3max(u2.v[j], u3.v[j], u4.v[j]))
                // row 4: vfB patch behind wave-uniform branch
                {
                    R8 mx4;
                    #pragma unroll
                    for (int j = 0; j < 8; ++j)
                        mx4.v[j] = f3max(u3.v[j], u4.v[j], beh.v[j]);
                    if (vwB) {
                        #pragma unroll
                        for (int j = 0; j < 8; ++j) {
                            float alt = fmaxf(u3.v[j], u4.v[j]);
                            mx4.v[j] = (gq == 3) ? alt : mx4.v[j];
                        }
                    }
                    UPD(4, mx4.v[j])
                }
                #undef UPD
                xb ^= 1;
            }
        }

        // ---- stash skeleton region [11,140]x[11,44] to LDS ----
        {
            float* SK = t ? SKT : SKP;
            #pragma unroll
            for (int i = 0; i < 5; ++i) {
                int pr = r0 + i;
                if (pr >= 11 && pr <= 140) {
                    #pragma unroll
                    for (int j = 0; j < 8; ++j) {
                        int pc = c0 + j;
                        if (pc >= 11 && pc <= 44)
                            SK[(pr - 11) * SKW + (pc - 11)] = A[i].v[j];
                    }
                }
            }
        }
    }
    __syncthreads();

    // ---- epilogue: rolling-column sumpool3 + indicators + loss ----
    // thread = column cx, 16 rows. SK row k holds global row ty0 + k - 1.
    const int cx  = tid & 31;
    const int ry0 = (tid >> 5) * 16;
    const int gx  = tx0 + cx;
    const float xl = (gx >= 1)      ? 1.0f : 0.0f;
    const float xr = (gx + 1 < IMG) ? 1.0f : 0.0f;

    auto hs = [&](const float* __restrict__ SK, int k) -> float {
        const float* p = SK + k * SKW + cx;   // p[0]=dx-1, p[1]=dx0, p[2]=dx+1
        return p[1] + xl * p[0] + xr * p[2];  // garbage finite, masked by 0
    };

    float acc = 0.0f;
    float hp0, hp1, ht0, ht1;
    {
        float vT = ((unsigned)(ty0 + ry0 - 1) < IMG) ? 1.0f : 0.0f;
        hp0 = vT * hs(SKP, ry0);
        ht0 = vT * hs(SKT, ry0);
        hp1 = hs(SKP, ry0 + 1);               // always in-image
        ht1 = hs(SKT, ry0 + 1);
    }
    #pragma unroll
    for (int r = 0; r < 16; ++r) {
        int k2 = ry0 + r + 2;
        float vB = ((unsigned)(ty0 + k2 - 1) < IMG) ? 1.0f : 0.0f;
        float hp2 = vB * hs(SKP, k2);
        float ht2 = vB * hs(SKT, k2);
        float pn = hp0 + hp1 + hp2;
        float tn = ht0 + ht1 + ht2;
        float ps = SKP[(ry0 + r + 1) * SKW + cx + 1];
        float ts = SKT[(ry0 + r + 1) * SKW + cx + 1];
        float pon = (ps > 0.5f) ? 1.0f : 0.0f;
        float ton = (ts > 0.5f) ? 1.0f : 0.0f;
        float pe = (pn == 2.0f) ? pon : 0.0f;
        float te = (tn == 2.0f) ? ton : 0.0f;
        float pc = (pn >= 4.0f) ? pon : 0.0f;
        float tc = (tn >= 4.0f) ? ton : 0.0f;
        float ds = ps - ts, de = pe - te, dc = pc - tc;
        acc += 0.6f * ds * ds + 0.2f * (de * de + dc * dc);
        hp0 = hp1; hp1 = hp2;
        ht0 = ht1; ht1 = ht2;
    }

    #pragma unroll
    for (int off = 32; off >= 1; off >>= 1)
        acc += __shfl_down(acc, off, 64);
    if ((tid & 63) == 0) red[tid >> 6] = acc;
    __syncthreads();
    if (tid == 0) {
        float sum = red[0] + red[1] + red[2] + red[3];
        atomicAdd(out, sum * (1.0f / 8388608.0f));  // N = 32*512*512 = 2^23
    }
}

extern "C" void kernel_launch(void* const* d_in, const int* in_sizes, int n_in,
                              void* d_out, int out_size, void* d_ws, size_t ws_size,
                              hipStream_t stream) {
    const float* pred   = (const float*)d_in[0];
    const float* target = (const float*)d_in[1];
    float* out = (float*)d_out;
    hipMemsetAsync(d_out, 0, sizeof(float) * (out_size > 0 ? out_size : 1), stream);
    const int nblocks = 32 * 64;   // 32 images x (4x16) tiles
    skel_conn_loss<<<nblocks, NT, 0, stream>>>(pred, target, out);
}

// Round 8
// 207.039 us; speedup vs baseline: 2.3466x; 2.3466x over previous
//
#include <hip/hip_runtime.h>

// ConnectivityLoss R8: R7's op cuts at R6's proven register economics.
// - launch_bounds(256,3): EMPIRICAL RULE (R5, R7): (256,4) makes the gfx950
//   backend allocate 64 VGPR and spill ~1.4 GB of scratch. (256,3) -> 84
//   VGPR, spill-free. Do not raise without checking WRITE_SIZE.
// - contour = maxpool3(B) - B exactly (center in window => mx >= B).
// - Border fixups behind block/wave-uniform branches: interior waves pay 0.

#define IMG 512
#define TW  32            // output tile width  (16 x-tiles)
#define TH  128           // output tile height (4 y-tiles)
#define SKW 34            // skeleton stash cols [11,44]
#define SKH 130           // skeleton stash rows [11,140]
#define XROW 68           // exchange row stride (floats)
#define XBUF (8*XROW)     // 4 waves x {top,bot}
#define NT  256

struct alignas(16) R8 { float v[8]; };

__device__ __forceinline__ float f3min(float a, float b, float c) {
    return fminf(fminf(a, b), c);
}
__device__ __forceinline__ float f3max(float a, float b, float c) {
    return fmaxf(fmaxf(a, b), c);
}
__device__ __forceinline__ float dpp_up1(float x) {   // lane i <- i-1
    int r = __builtin_amdgcn_update_dpp(
        0, __builtin_bit_cast(int, x), 0x111, 0xF, 0xF, true); // row_shr:1
    return __builtin_bit_cast(float, r);
}
__device__ __forceinline__ float dpp_dn1(float x) {   // lane i <- i+1
    int r = __builtin_amdgcn_update_dpp(
        0, __builtin_bit_cast(int, x), 0x101, 0xF, 0xF, true); // row_shl:1
    return __builtin_bit_cast(float, r);
}
__device__ __forceinline__ float bpermf(int addr, float x) {
    return __builtin_bit_cast(float,
        __builtin_amdgcn_ds_bpermute(addr, __builtin_bit_cast(int, x)));
}

// horizontal 3-tap; le/ri from strip s-1/s+1 (lane -8/+8).
// Image-edge tap-drop only inside block-uniform lB/rB branches.
template<bool MN>
__device__ __forceinline__ void hrow(const R8& r, R8& h, bool lB, bool rB,
                                     int s, int aL, int aR) {
    float le = bpermf(aL, r.v[7]);
    float ri = bpermf(aR, r.v[0]);
    if (MN) {
        h.v[0] = f3min(le,     r.v[0], r.v[1]);
        h.v[1] = f3min(r.v[0], r.v[1], r.v[2]);
        h.v[2] = f3min(r.v[1], r.v[2], r.v[3]);
        h.v[3] = f3min(r.v[2], r.v[3], r.v[4]);
        h.v[4] = f3min(r.v[3], r.v[4], r.v[5]);
        h.v[5] = f3min(r.v[4], r.v[5], r.v[6]);
        h.v[6] = f3min(r.v[5], r.v[6], r.v[7]);
        h.v[7] = f3min(r.v[6], r.v[7], ri);
        if (lB) { if (s == 1) h.v[4] = fminf(r.v[4], r.v[5]); }  // gx==0
        if (rB) { if (s == 5) h.v[3] = fminf(r.v[2], r.v[3]); }  // gx==511
    } else {
        h.v[0] = f3max(le,     r.v[0], r.v[1]);
        h.v[1] = f3max(r.v[0], r.v[1], r.v[2]);
        h.v[2] = f3max(r.v[1], r.v[2], r.v[3]);
        h.v[3] = f3max(r.v[2], r.v[3], r.v[4]);
        h.v[4] = f3max(r.v[3], r.v[4], r.v[5]);
        h.v[5] = f3max(r.v[4], r.v[5], r.v[6]);
        h.v[6] = f3max(r.v[5], r.v[6], r.v[7]);
        h.v[7] = f3max(r.v[6], r.v[7], ri);
        if (lB) { if (s == 1) h.v[4] = fmaxf(r.v[4], r.v[5]); }
        if (rB) { if (s == 5) h.v[3] = fmaxf(r.v[2], r.v[3]); }
    }
}

__global__ __launch_bounds__(NT, 3)
void skel_conn_loss(const float* __restrict__ pred,
                    const float* __restrict__ target,
                    float* __restrict__ out)
{
    __shared__ float X[2*XBUF];          // boundary-row exchange dbuf (4.35KB)
    __shared__ float SKP[SKH*SKW];       // pred skeleton
    __shared__ float SKT[SKH*SKW];       // target skeleton
    __shared__ float red[4];

    const int tid  = threadIdx.x;
    const int wv   = tid >> 6;           // wave 0..3 owns rows 40w..40w+39
    const int lane = tid & 63;
    const int s    = lane >> 3;          // 8-col strip
    const int gq   = lane & 7;           // row group (5 rows); +-1 == lane+-1
    const int img  = blockIdx.x >> 6;
    const int rem  = blockIdx.x & 63;
    const int ty0  = (rem >> 4) * TH;
    const int tx0  = (rem & 15) * TW;

    const int c0  = 8*s;
    const int r0  = 40*wv + 5*gq;
    const int gx0 = tx0 - 12 + c0;
    const bool xin = (tx0 > 0) && (tx0 + TW < IMG);

    const bool lB = (tx0 == 0), rB = (tx0 + TW == IMG);        // block-uniform
    const bool vwT = (ty0 == 0)       && (wv == 0);            // wave-uniform
    const bool vwB = (ty0 + TH == IMG) && (wv == 3);
    const int  sw  = 8*s + 4*(s >> 2);               // bank-swizzled exch col
    const int  aL  = ((lane - 8) & 63) * 4;          // bpermute addrs
    const int  aR  = ((lane + 8) & 63) * 4;

    R8 A[5], Bv[5];
    int xb = 0;

    #pragma unroll 1
    for (int t = 0; t < 2; ++t) {
        const float* __restrict__ src =
            (t ? target : pred) + (size_t)img * (IMG * IMG);

        // ---- load strip (addresses clamped; OOB values never consumed) ----
        #pragma unroll
        for (int i = 0; i < 5; ++i) {
            int gy = min(max(ty0 - 12 + r0 + i, 0), IMG - 1);
            const float* rp = src + gy * IMG;
            if (xin) {
                *(float4*)&A[i].v[0] = *(const float4*)(rp + gx0);
                *(float4*)&A[i].v[4] = *(const float4*)(rp + gx0 + 4);
            } else {
                #pragma unroll
                for (int j = 0; j < 8; ++j)
                    A[i].v[j] = rp[min(max(gx0 + j, 0), IMG - 1)];
            }
        }

        #pragma unroll 1
        for (int it = 0; it < 5; ++it) {
            // ================= pass 1: Bv = minpool3(A) =================
            {
                R8 w0, w1, w2, w3, w4, abh, beh;
                hrow<true>(A[4], w4, lB, rB, s, aL, aR);   // feeds exch+DPP
                hrow<true>(A[0], w0, lB, rB, s, aL, aR);
                float* Xb = X + xb * XBUF;
                if (gq == 0) {
                    float* p = Xb + (2*wv) * XROW + sw;
                    *(float4*)p       = *(const float4*)&w0.v[0];
                    *(float4*)(p + 4) = *(const float4*)&w0.v[4];
                }
                if (gq == 7) {
                    float* p = Xb + (2*wv + 1) * XROW + sw;
                    *(float4*)p       = *(const float4*)&w4.v[0];
                    *(float4*)(p + 4) = *(const float4*)&w4.v[4];
                }
                __syncthreads();
                #pragma unroll
                for (int j = 0; j < 8; ++j) {
                    abh.v[j] = dpp_up1(w4.v[j]);   // group above's bottom
                    beh.v[j] = dpp_dn1(w0.v[j]);   // group below's top
                }
                if (gq == 0) {
                    if (wv) {
                        const float* p = Xb + (2*wv - 1) * XROW + sw;
                        *(float4*)&abh.v[0] = *(const float4*)p;
                        *(float4*)&abh.v[4] = *(const float4*)(p + 4);
                    } else abh = w0;               // tile-edge garbage margin
                }
                if (gq == 7) {
                    if (wv < 3) {
                        const float* p = Xb + (2*wv + 2) * XROW + sw;
                        *(float4*)&beh.v[0] = *(const float4*)p;
                        *(float4*)&beh.v[4] = *(const float4*)(p + 4);
                    } else beh = w4;
                }
                hrow<true>(A[1], w1, lB, rB, s, aL, aR);
                #pragma unroll
                for (int j = 0; j < 8; ++j)
                    Bv[0].v[j] = f3min(abh.v[j], w0.v[j], w1.v[j]);
                hrow<true>(A[2], w2, lB, rB, s, aL, aR);
                #pragma unroll
                for (int j = 0; j < 8; ++j)
                    Bv[1].v[j] = f3min(w0.v[j], w1.v[j], w2.v[j]);
                hrow<true>(A[3], w3, lB, rB, s, aL, aR);
                #pragma unroll
                for (int j = 0; j < 8; ++j) {
                    Bv[2].v[j] = f3min(w1.v[j], w2.v[j], w3.v[j]);
                    Bv[3].v[j] = f3min(w2.v[j], w3.v[j], w4.v[j]);
                    Bv[4].v[j] = f3min(w3.v[j], w4.v[j], beh.v[j]);
                }
                if (vwT) {               // wave-uniform: row 12 == gy 0
                    #pragma unroll
                    for (int j = 0; j < 8; ++j) {
                        float alt = fminf(w2.v[j], w3.v[j]);
                        Bv[2].v[j] = (gq == 2) ? alt : Bv[2].v[j];
                    }
                }
                if (vwB) {               // wave-uniform: row 139 == gy 511
                    #pragma unroll
                    for (int j = 0; j < 8; ++j) {
                        float alt = fminf(w3.v[j], w4.v[j]);
                        Bv[4].v[j] = (gq == 3) ? alt : Bv[4].v[j];
                    }
                }
                xb ^= 1;
            }
            // == pass 2: A = relu(A - (maxpool3(Bv) - Bv)), mx>=Bv exact ==
            {
                R8 u0, u1, u2, u3, u4, abh, beh;
                hrow<false>(Bv[4], u4, lB, rB, s, aL, aR);
                hrow<false>(Bv[0], u0, lB, rB, s, aL, aR);
                float* Xb = X + xb * XBUF;
                if (gq == 0) {
                    float* p = Xb + (2*wv) * XROW + sw;
                    *(float4*)p       = *(const float4*)&u0.v[0];
                    *(float4*)(p + 4) = *(const float4*)&u0.v[4];
                }
                if (gq == 7) {
                    float* p = Xb + (2*wv + 1) * XROW + sw;
                    *(float4*)p       = *(const float4*)&u4.v[0];
                    *(float4*)(p + 4) = *(const float4*)&u4.v[4];
                }
                __syncthreads();
                #pragma unroll
                for (int j = 0; j < 8; ++j) {
                    abh.v[j] = dpp_up1(u4.v[j]);
                    beh.v[j] = dpp_dn1(u0.v[j]);
                }
                if (gq == 0) {
                    if (wv) {
                        const float* p = Xb + (2*wv - 1) * XROW + sw;
                        *(float4*)&abh.v[0] = *(const float4*)p;
                        *(float4*)&abh.v[4] = *(const float4*)(p + 4);
                    } else abh = u0;
                }
                if (gq == 7) {
                    if (wv < 3) {
                        const float* p = Xb + (2*wv + 2) * XROW + sw;
                        *(float4*)&beh.v[0] = *(const float4*)p;
                        *(float4*)&beh.v[4] = *(const float4*)(p + 4);
                    } else beh = u4;
                }
                // ct = mx - Bv (>=0 exactly); A = max(A - ct, 0)
                #define UPD(i, MXE)                                            \
                    _Pragma("unroll")                                          \
                    for (int j = 0; j < 8; ++j) {                              \
                        float ct = (MXE) - Bv[i].v[j];                         \
                        A[i].v[j] = fmaxf(A[i].v[j] - ct, 0.0f);               \
                    }
                hrow<false>(Bv[1], u1, lB, rB, s, aL, aR);
                UPD(0, f3max(abh.v[j], u0.v[j], u1.v[j]))
                hrow<false>(Bv[2], u2, lB, rB, s, aL, aR);
                UPD(1, f3max(u0.v[j], u1.v[j], u2.v[j]))
                hrow<false>(Bv[3], u3, lB, rB, s, aL, aR);
                // row 2: vfT patch behind wave-uniform branch
                {
                    R8 mx2;
                    #pragma unroll
                    for (int j = 0; j < 8; ++j)
                        mx2.v[j] = f3max(u1.v[j], u2.v[j], u3.v[j]);
                    if (vwT) {
                        #pragma unroll
                        for (int j = 0; j < 8; ++j) {
                            float alt = fmaxf(u2.v[j], u3.v[j]);
                            mx2.v[j] = (gq == 2) ? alt : mx2.v[j];
                        }
                    }
                    UPD(2, mx2.v[j])
                }
                UPD(3, f3max(u2.v[j], u3.v[j], u4.v[j]))
                // row 4: vfB patch behind wave-uniform branch
                {
                    R8 mx4;
                    #pragma unroll
                    for (int j = 0; j < 8; ++j)
                        mx4.v[j] = f3max(u3.v[j], u4.v[j], beh.v[j]);
                    if (vwB) {
                        #pragma unroll
                        for (int j = 0; j < 8; ++j) {
                            float alt = fmaxf(u3.v[j], u4.v[j]);
                            mx4.v[j] = (gq == 3) ? alt : mx4.v[j];
                        }
                    }
                    UPD(4, mx4.v[j])
                }
                #undef UPD
                xb ^= 1;
            }
        }

        // ---- stash skeleton region [11,140]x[11,44] to LDS ----
        {
            float* SK = t ? SKT : SKP;
            #pragma unroll
            for (int i = 0; i < 5; ++i) {
                int pr = r0 + i;
                if (pr >= 11 && pr <= 140) {
                    #pragma unroll
                    for (int j = 0; j < 8; ++j) {
                        int pc = c0 + j;
                        if (pc >= 11 && pc <= 44)
                            SK[(pr - 11) * SKW + (pc - 11)] = A[i].v[j];
                    }
                }
            }
        }
    }
    __syncthreads();

    // ---- epilogue: rolling-column sumpool3 + indicators + loss ----
    // thread = column cx, 16 rows. SK row k holds global row ty0 + k - 1.
    const int cx  = tid & 31;
    const int ry0 = (tid >> 5) * 16;
    const int gx  = tx0 + cx;
    const float xl = (gx >= 1)      ? 1.0f : 0.0f;
    const float xr = (gx + 1 < IMG) ? 1.0f : 0.0f;

    auto hs = [&](const float* __restrict__ SK, int k) -> float {
        const float* p = SK + k * SKW + cx;   // p[0]=dx-1, p[1]=dx0, p[2]=dx+1
        return p[1] + xl * p[0] + xr * p[2];  // garbage finite, masked by 0
    };

    float acc = 0.0f;
    float hp0, hp1, ht0, ht1;
    {
        float vT = ((unsigned)(ty0 + ry0 - 1) < IMG) ? 1.0f : 0.0f;
        hp0 = vT * hs(SKP, ry0);
        ht0 = vT * hs(SKT, ry0);
        hp1 = hs(SKP, ry0 + 1);               // always in-image
        ht1 = hs(SKT, ry0 + 1);
    }
    #pragma unroll
    for (int r = 0; r < 16; ++r) {
        int k2 = ry0 + r + 2;
        float vB = ((unsigned)(ty0 + k2 - 1) < IMG) ? 1.0f : 0.0f;
        float hp2 = vB * hs(SKP, k2);
        float ht2 = vB * hs(SKT, k2);
        float pn = hp0 + hp1 + hp2;
        float tn = ht0 + ht1 + ht2;
        float ps = SKP[(ry0 + r + 1) * SKW + cx + 1];
        float ts = SKT[(ry0 + r + 1) * SKW + cx + 1];
        float pon = (ps > 0.5f) ? 1.0f : 0.0f;
        float ton = (ts > 0.5f) ? 1.0f : 0.0f;
        float pe = (pn == 2.0f) ? pon : 0.0f;
        float te = (tn == 2.0f) ? ton : 0.0f;
        float pc = (pn >= 4.0f) ? pon : 0.0f;
        float tc = (tn >= 4.0f) ? ton : 0.0f;
        float ds = ps - ts, de = pe - te, dc = pc - tc;
        acc += 0.6f * ds * ds + 0.2f * (de * de + dc * dc);
        hp0 = hp1; hp1 = hp2;
        ht0 = ht1; ht1 = ht2;
    }

    #pragma unroll
    for (int off = 32; off >= 1; off >>= 1)
        acc += __shfl_down(acc, off, 64);
    if ((tid & 63) == 0) red[tid >> 6] = acc;
    __syncthreads();
    if (tid == 0) {
        float sum = red[0] + red[1] + red[2] + red[3];
        atomicAdd(out, sum * (1.0f / 8388608.0f));  // N = 32*512*512 = 2^23
    }
}

extern "C" void kernel_launch(void* const* d_in, const int* in_sizes, int n_in,
                              void* d_out, int out_size, void* d_ws, size_t ws_size,
                              hipStream_t stream) {
    const float* pred   = (const float*)d_in[0];
    const float* target = (const float*)d_in[1];
    float* out = (float*)d_out;
    hipMemsetAsync(d_out, 0, sizeof(float) * (out_size > 0 ? out_size : 1), stream);
    const int nblocks = 32 * 64;   // 32 images x (4x16) tiles
    skel_conn_loss<<<nblocks, NT, 0, stream>>>(pred, target, out);
}